// Round 2
// baseline (1859.931 us; speedup 1.0000x reference)
//
#include <hip/hip_runtime.h>
#include <math.h>

#define CIN   3
#define DD    32
#define HH    128
#define WW    128
#define COUTC 24
#define HP    126
#define WP    126

#define TPX    16          // pixel-groups per cout
#define PPT    4           // pixels per thread (along w')
#define TILE_W 64          // TPX * PPT
#define NTH    384         // COUTC * TPX
#define LDSROW 68          // padded row stride (16B aligned)

// One depth slice: stage 3x3x66 input rows into LDS, accumulate contributions
// into the 3-slot ring of partial conv outputs. S0/S1/S2 are the compile-time
// ring slots for d' = d, d-1, d-2 (S0 = d%3, S1 = (d+2)%3, S2 = (d+1)%3).
template<int S0, int S1, int S2>
__device__ __forceinline__ void do_slice(
    int d, int t, int bb, int hp, int w0, int pw,
    const float* __restrict__ x,
    const float (&w_r)[81],
    float (&ring)[PPT][3],
    float (&mn)[PPT],
    float* __restrict__ lds_x)
{
  __syncthreads();
  // stage slice d: 3 cin x 3 rows x 66 cols
  for (int idx = t; idx < 3 * 3 * 66; idx += NTH) {
    int ci  = idx / 198;
    int r   = idx - ci * 198;
    int kh  = r / 66;
    int col = r - kh * 66;
    int gcol = w0 + col;
    gcol = gcol > (WW - 1) ? (WW - 1) : gcol;   // clamp (unused by valid pixels)
    lds_x[(ci * 3 + kh) * LDSROW + col] =
        x[(((size_t)(bb * CIN + ci) * DD + d) * HH + (hp + kh)) * WW + gcol];
  }
  __syncthreads();

  // read this thread's 3x3x6 patch (covers its 4 pixels)
  float p[3][3][6];
  #pragma unroll
  for (int ci = 0; ci < 3; ++ci) {
    #pragma unroll
    for (int kh = 0; kh < 3; ++kh) {
      const float* rp = &lds_x[(ci * 3 + kh) * LDSROW + 4 * pw];
      float4 a  = *(const float4*)rp;
      float2 b2 = *(const float2*)(rp + 4);
      p[ci][kh][0] = a.x;  p[ci][kh][1] = a.y;
      p[ci][kh][2] = a.z;  p[ci][kh][3] = a.w;
      p[ci][kh][4] = b2.x; p[ci][kh][5] = b2.y;
    }
  }

  // kd = 0 contributes to conv[d]   (slot S0) -- also starts it (zero)
  if (d <= 29) {
    #pragma unroll
    for (int q = 0; q < PPT; ++q) ring[q][S0] = 0.0f;
    #pragma unroll
    for (int ci = 0; ci < 3; ++ci)
      #pragma unroll
      for (int kh = 0; kh < 3; ++kh)
        #pragma unroll
        for (int kw = 0; kw < 3; ++kw) {
          float wv = w_r[((ci * 3 + kh) * 3 + kw) * 3 + 0];
          #pragma unroll
          for (int q = 0; q < PPT; ++q)
            ring[q][S0] = fmaf(p[ci][kh][kw + q], wv, ring[q][S0]);
        }
  }
  // kd = 1 contributes to conv[d-1] (slot S1)
  if (d >= 1 && d <= 30) {
    #pragma unroll
    for (int ci = 0; ci < 3; ++ci)
      #pragma unroll
      for (int kh = 0; kh < 3; ++kh)
        #pragma unroll
        for (int kw = 0; kw < 3; ++kw) {
          float wv = w_r[((ci * 3 + kh) * 3 + kw) * 3 + 1];
          #pragma unroll
          for (int q = 0; q < PPT; ++q)
            ring[q][S1] = fmaf(p[ci][kh][kw + q], wv, ring[q][S1]);
        }
  }
  // kd = 2 contributes to conv[d-2] (slot S2) -- completes it -> take min
  if (d >= 2) {
    #pragma unroll
    for (int ci = 0; ci < 3; ++ci)
      #pragma unroll
      for (int kh = 0; kh < 3; ++kh)
        #pragma unroll
        for (int kw = 0; kw < 3; ++kw) {
          float wv = w_r[((ci * 3 + kh) * 3 + kw) * 3 + 2];
          #pragma unroll
          for (int q = 0; q < PPT; ++q)
            ring[q][S2] = fmaf(p[ci][kh][kw + q], wv, ring[q][S2]);
        }
    #pragma unroll
    for (int q = 0; q < PPT; ++q)
      mn[q] = fminf(mn[q], ring[q][S2]);
  }
}

__global__ __launch_bounds__(NTH, 2)
void conv3d_min_softmax_kernel(const float* __restrict__ x,
                               const float* __restrict__ wgt,
                               const float* __restrict__ bias,
                               float* __restrict__ out)
{
  __shared__ __align__(16) float lds_x[3 * 3 * LDSROW];
  __shared__ float lds_sm[TILE_W][COUTC];
  __shared__ float lds_mx[TILE_W];
  __shared__ float lds_rs[TILE_W];

  const int t  = threadIdx.x;
  const int c  = t / TPX;            // this thread's output channel
  const int pw = t - c * TPX;        // pixel group (4 consecutive w')
  const int w0 = blockIdx.x * TILE_W;
  const int hp = blockIdx.y;         // output row h'
  const int bb = blockIdx.z;         // batch

  // weights for channel c, rearranged so kd is fastest: w_r[(ci*9+kh*3+kw)*3+kd]
  float w_r[81];
  {
    const float* wc = wgt + c * (CIN * 27);
    #pragma unroll
    for (int ci = 0; ci < 3; ++ci)
      #pragma unroll
      for (int kd = 0; kd < 3; ++kd)
        #pragma unroll
        for (int kh = 0; kh < 3; ++kh)
          #pragma unroll
          for (int kw = 0; kw < 3; ++kw)
            w_r[((ci * 3 + kh) * 3 + kw) * 3 + kd] =
                wc[((ci * 3 + kd) * 3 + kh) * 3 + kw];
  }

  float ring[PPT][3];
  float mn[PPT];
  #pragma unroll
  for (int q = 0; q < PPT; ++q) mn[q] = INFINITY;

  // stream the 32 depth slices; ring slots fixed at compile time (d0 % 3 == 0)
  for (int d0 = 0; d0 < DD; d0 += 3) {
    do_slice<0, 2, 1>(d0, t, bb, hp, w0, pw, x, w_r, ring, mn, lds_x);
    if (d0 + 1 < DD)
      do_slice<1, 0, 2>(d0 + 1, t, bb, hp, w0, pw, x, w_r, ring, mn, lds_x);
    if (d0 + 2 < DD)
      do_slice<2, 1, 0>(d0 + 2, t, bb, hp, w0, pw, x, w_r, ring, mn, lds_x);
  }

  // epilogue: min-over-depth done; add bias, softmax over the 24 channels
  const float bval = bias[c];
  float val[PPT];
  #pragma unroll
  for (int q = 0; q < PPT; ++q) val[q] = mn[q] + bval;

  __syncthreads();
  #pragma unroll
  for (int q = 0; q < PPT; ++q)
    lds_sm[pw * PPT + q][c] = val[q];
  __syncthreads();

  if (t < TILE_W) {
    float mx = -INFINITY;
    #pragma unroll
    for (int cc = 0; cc < COUTC; ++cc) mx = fmaxf(mx, lds_sm[t][cc]);
    float s = 0.0f;
    #pragma unroll
    for (int cc = 0; cc < COUTC; ++cc) s += __expf(lds_sm[t][cc] - mx);
    lds_mx[t] = mx;
    lds_rs[t] = 1.0f / s;
  }
  __syncthreads();

  #pragma unroll
  for (int q = 0; q < PPT; ++q) {
    int wp_ = w0 + pw * PPT + q;
    if (wp_ < WP) {
      int pix = pw * PPT + q;
      float o = __expf(val[q] - lds_mx[pix]) * lds_rs[pix];
      out[(((size_t)bb * COUTC + c) * HP + hp) * WP + wp_] = o;
    }
  }
}

extern "C" void kernel_launch(void* const* d_in, const int* in_sizes, int n_in,
                              void* d_out, int out_size, void* d_ws, size_t ws_size,
                              hipStream_t stream)
{
  const float* x    = (const float*)d_in[0];
  const float* wgt  = (const float*)d_in[1];
  const float* bias = (const float*)d_in[2];
  float* out = (float*)d_out;

  dim3 grid(2, HP, 16);   // 2 w-tiles of 64, 126 rows, 16 batches
  dim3 block(NTH);
  hipLaunchKernelGGL(conv3d_min_softmax_kernel, grid, block, 0, stream,
                     x, wgt, bias, out);
}